// Round 8
// baseline (137.862 us; speedup 1.0000x reference)
//
#include <hip/hip_runtime.h>

#define DIM 1024
#define SEQ 2048
#define HID 128
#define HEADS 8
#define DECAYC 4
#define CHUNK 32
#define NCH (SEQ / CHUNK)  // 64
#define BK 64
#define NT (DIM / BK)      // 16 K-tiles (256x256 kernel)

typedef __bf16 bf16x8 __attribute__((ext_vector_type(8)));
typedef float f32x4 __attribute__((ext_vector_type(4)));
typedef unsigned short u16x4 __attribute__((ext_vector_type(4)));

__device__ __forceinline__ unsigned short f2bf(float f) {
  union { float f; unsigned u; } v; v.f = f;
  unsigned r = v.u + 0x7fffu + ((v.u >> 16) & 1u);
  return (unsigned short)(r >> 16);
}
__device__ __forceinline__ float bf2f(unsigned short u) {
  union { unsigned u; float f; } v; v.u = ((unsigned)u) << 16;
  return v.f;
}

typedef __attribute__((address_space(1))) const unsigned int* g_u32p;
typedef __attribute__((address_space(3))) unsigned int* l_u32p;

__device__ __forceinline__ void async_ld16(const unsigned short* g, unsigned short* l) {
  __builtin_amdgcn_global_load_lds((g_u32p)g, (l_u32p)l, 16, 0, 0);
}

// ---------------- fp32 -> bf16 convert (both weights, one launch) ----------------
__global__ void convertk2(const float* __restrict__ in0, unsigned short* __restrict__ out0,
                          const float* __restrict__ in1, unsigned short* __restrict__ out1,
                          int n) {
  int i = blockIdx.x * 256 + threadIdx.x;
  if (i < n) {
    out0[i] = f2bf(in0[i]);
    out1[i] = f2bf(in1[i]);
  }
}

// ------------- x (B,E,T) f32 -> xT (B,T,E) bf16 (vectorized writes) -------------
__global__ __launch_bounds__(256) void transpose_x(const float* __restrict__ x,
                                                   unsigned short* __restrict__ xT) {
  __shared__ float tile[64][65];
  const int b = blockIdx.z;
  const int e0 = blockIdx.x * 64;
  const int t0 = blockIdx.y * 64;
  const int tr = threadIdx.x >> 6;
  const int tc = threadIdx.x & 63;
  const float* xp = x + ((size_t)b * DIM + e0) * SEQ + t0;
#pragma unroll
  for (int i = 0; i < 16; ++i) {
    int e = i * 4 + tr;
    tile[e][tc] = xp[(size_t)e * SEQ + tc];
  }
  __syncthreads();
  unsigned short* op = xT + ((size_t)b * SEQ + t0) * DIM + e0;
  const int tq = threadIdx.x >> 4;        // 0..15 (t within group)
  const int e4 = (threadIdx.x & 15) * 4;  // 0..60
#pragma unroll
  for (int i = 0; i < 4; ++i) {
    int t = i * 16 + tq;
    u16x4 ov;
    ov[0] = f2bf(tile[e4 + 0][t]);
    ov[1] = f2bf(tile[e4 + 1][t]);
    ov[2] = f2bf(tile[e4 + 2][t]);
    ov[3] = f2bf(tile[e4 + 3][t]);
    *(u16x4*)&op[(size_t)t * DIM + e4] = ov;
  }
}

// ------------- 256x256 8-phase pipelined NT GEMM (R6-VAR0 control) -------------
template <int C_BF16, int BIAS_ROW, int MODE>
__global__ __launch_bounds__(512, 2) void gemm256(const unsigned short* __restrict__ A,
                                                  const unsigned short* __restrict__ B,
                                                  void* __restrict__ Cv,
                                                  const float* __restrict__ bias,
                                                  int ldc, long sB, long sC) {
  __shared__ unsigned short lds[65536];  // 128 KiB

  int m0, n0, z;
  if constexpr (MODE == 1) {
    m0 = (blockIdx.x >> 2) * 256;
    n0 = (blockIdx.x & 3) * 256;
    z = 0;
  } else {
    z = blockIdx.x >> 5;
    m0 = ((blockIdx.x >> 3) & 3) * 256;
    n0 = (blockIdx.x & 7) * 256;
  }
  B += (size_t)sB * z;

  const int tid = threadIdx.x;
  const int lane = tid & 63;
  const int w = tid >> 6;
  const int wm = w >> 2;
  const int wn = w & 3;

  const unsigned short* sp[2][2][2];
#pragma unroll
  for (int j = 0; j < 2; ++j) {
    int c = (w * 2 + j) * 1024 + lane * 16;
    int cs = c ^ (((c >> 7) & 3) << 4);
    int row = cs >> 6;
    int colel = (cs & 63) >> 1;
#pragma unroll
    for (int kh = 0; kh < 2; ++kh) {
      sp[0][kh][j] = A + (size_t)(m0 + row) * DIM + kh * 32 + colel;
      sp[1][kh][j] = B + (size_t)(n0 + row) * DIM + kh * 32 + colel;
    }
  }

  const int r15 = lane & 15;
  const int hi = lane >> 4;
  const int rsw = ((r15 >> 1) & 3) << 4;
  int aoff[8][2], boff[4][2];
#pragma unroll
  for (int fi = 0; fi < 8; ++fi) {
    int byte = ((wm * 128 + fi * 16 + r15) * 64 + hi * 16) ^ rsw;
#pragma unroll
    for (int ks = 0; ks < 2; ++ks) aoff[fi][ks] = ks * 8192 + (byte >> 1);
  }
#pragma unroll
  for (int fj = 0; fj < 4; ++fj) {
    int byte = ((wn * 64 + fj * 16 + r15) * 64 + hi * 16) ^ rsw;
#pragma unroll
    for (int ks = 0; ks < 2; ++ks) boff[fj][ks] = 16384 + ks * 8192 + (byte >> 1);
  }

  f32x4 acc[8][4] = {};

#define STG(dd, op, kh, tgt)                                                    \
  if ((tgt) < NT) {                                                             \
    unsigned short* dst_ = (unsigned short*)lds + (dd) * 32768 + (op) * 16384 + \
                           (kh) * 8192 + w * 1024;                              \
    async_ld16(sp[op][kh][0] + (tgt) * BK, dst_);                               \
    async_ld16(sp[op][kh][1] + (tgt) * BK, dst_ + 512);                         \
  }

#define PHASE(H_, KS_, MIDBAR, STAGE_STMT)                                      \
  {                                                                             \
    bf16x8 af[4], bfr[4];                                                       \
    _Pragma("unroll") for (int i = 0; i < 4; ++i)                               \
        af[i] = *(const bf16x8*)&lb[aoff[(H_) * 4 + i][KS_]];                   \
    _Pragma("unroll") for (int j = 0; j < 4; ++j)                               \
        bfr[j] = *(const bf16x8*)&lb[boff[j][KS_]];                             \
    STAGE_STMT;                                                                 \
    if (MIDBAR) __builtin_amdgcn_s_barrier();                                   \
    asm volatile("s_waitcnt lgkmcnt(0)" ::: "memory");                          \
    __builtin_amdgcn_sched_barrier(0);                                          \
    __builtin_amdgcn_s_setprio(1);                                              \
    _Pragma("unroll") for (int i = 0; i < 4; ++i)                               \
      _Pragma("unroll") for (int j = 0; j < 4; ++j)                             \
        acc[(H_) * 4 + i][j] = __builtin_amdgcn_mfma_f32_16x16x32_bf16(         \
            af[i], bfr[j], acc[(H_) * 4 + i][j], 0, 0, 0);                      \
    __builtin_amdgcn_s_setprio(0);                                              \
    __builtin_amdgcn_s_barrier();                                               \
  }

  STG(0, 0, 0, 0); STG(0, 1, 0, 0); STG(0, 0, 1, 0); STG(0, 1, 1, 0);
  STG(1, 0, 0, 1); STG(1, 1, 0, 1);

#pragma unroll
  for (int t = 0; t < NT; ++t) {
    const int d = t & 1;
    const unsigned short* lb = (const unsigned short*)lds + d * 32768;
    if (t == NT - 1) {
      asm volatile("s_waitcnt vmcnt(0)" ::: "memory");
    } else {
      asm volatile("s_waitcnt vmcnt(4)" ::: "memory");
    }
    __builtin_amdgcn_s_barrier();
    PHASE(0, 0, 0, STG(d ^ 1, 0, 1, t + 1));
    PHASE(1, 0, 1, STG(d ^ 1, 1, 1, t + 1));
    PHASE(0, 1, 1, STG(d, 0, 0, t + 2));
    PHASE(1, 1, 1, STG(d, 1, 0, t + 2));
  }
#undef PHASE
#undef STG

  const int or0 = hi * 4;
#pragma unroll
  for (int fi = 0; fi < 8; ++fi) {
#pragma unroll
    for (int fj = 0; fj < 4; ++fj) {
      const int col = n0 + wn * 64 + fj * 16 + r15;
      const int rowb = m0 + wm * 128 + fi * 16 + or0;
      float cb = BIAS_ROW ? 0.0f : bias[col];
#pragma unroll
      for (int q = 0; q < 4; ++q) {
        const int row = rowb + q;
        float v = acc[fi][fj][q] + (BIAS_ROW ? bias[row] : cb);
        if constexpr (C_BF16) {
          ((unsigned short*)Cv)[(size_t)sC * z + (size_t)row * ldc + col] = f2bf(v);
        } else {
          ((float*)Cv)[(size_t)sC * z + (size_t)row * ldc + col] = v;
        }
      }
    }
  }
}

// ------------- NEW: 256x128 tile, BK=32, 2 blocks/CU NT GEMM -------------
// 8 waves (2M x 4N), per-wave 128x32. LDS 48KB: [2 buf][A 16KB | B 8KB].
// One barrier + vmcnt(0) per K-tile; co-resident block hides the stalls.
template <int C_BF16, int BIAS_ROW, int MODE>
__global__ __launch_bounds__(512, 4) void gemm128n(const unsigned short* __restrict__ A,
                                                   const unsigned short* __restrict__ B,
                                                   void* __restrict__ Cv,
                                                   const float* __restrict__ bias,
                                                   int ldc, long sB, long sC) {
  __shared__ unsigned short lds[24576];  // 48 KiB (12288 ushorts per buf)

  int m0, n0, z;
  if constexpr (MODE == 1) {
    m0 = (blockIdx.x >> 3) * 256;       // 64 m-tiles
    n0 = (blockIdx.x & 7) * 128;        // 8 n-tiles
    z = 0;
  } else {
    z = blockIdx.x >> 6;                // 8 batches
    m0 = ((blockIdx.x >> 4) & 3) * 256; // 4 m-tiles
    n0 = (blockIdx.x & 15) * 128;       // 16 n-tiles
  }
  B += (size_t)sB * z;

  const int tid = threadIdx.x;
  const int lane = tid & 63;
  const int w = tid >> 6;
  const int wm = w >> 2;  // 0..1
  const int wn = w & 3;   // 0..3

  // staging sources (inverse-swizzled; 64B rows, XOR bits 4-5 by row bits 1-2)
  int c0 = tid * 16;
  int c1 = 8192 + tid * 16;
  int c2 = tid * 16;
  int cs0 = c0 ^ (((c0 >> 7) & 3) << 4);
  int cs1 = c1 ^ (((c1 >> 7) & 3) << 4);
  int cs2 = c2 ^ (((c2 >> 7) & 3) << 4);
  const unsigned short* srcA0 = A + (size_t)(m0 + (cs0 >> 6)) * DIM + ((cs0 & 63) >> 1);
  const unsigned short* srcA1 = A + (size_t)(m0 + (cs1 >> 6)) * DIM + ((cs1 & 63) >> 1);
  const unsigned short* srcB0 = B + (size_t)(n0 + (cs2 >> 6)) * DIM + ((cs2 & 63) >> 1);

  // fragment read bases (ushort index); frag fi at abase + fi*512, fj at bbase + fj*512
  const int r15 = lane & 15;
  const int hi = lane >> 4;
  const int rsw = ((r15 >> 1) & 3) << 4;
  const int abase = ((((wm * 128 + r15) * 64) + hi * 16) ^ rsw) >> 1;
  const int bbase = 8192 + (((((wn * 32 + r15) * 64) + hi * 16) ^ rsw) >> 1);

  f32x4 acc[8][2] = {};

#define STG2(dd, k)                                                \
  {                                                                \
    unsigned short* bb_ = (unsigned short*)lds + (dd) * 12288;     \
    async_ld16(srcA0 + (k), bb_ + tid * 8);                        \
    async_ld16(srcA1 + (k), bb_ + 4096 + tid * 8);                 \
    async_ld16(srcB0 + (k), bb_ + 8192 + tid * 8);                 \
  }

  STG2(0, 0);
  asm volatile("s_waitcnt vmcnt(0)" ::: "memory");
  __builtin_amdgcn_s_barrier();

#pragma unroll 2
  for (int t = 0; t < 32; ++t) {
    const int d = t & 1;
    const unsigned short* lb = (const unsigned short*)lds + d * 12288;
    if (t < 31) STG2(d ^ 1, (t + 1) * 32);
    bf16x8 bf0 = *(const bf16x8*)&lb[bbase];
    bf16x8 bf1 = *(const bf16x8*)&lb[bbase + 512];
    bf16x8 af[4];
#pragma unroll
    for (int fi = 0; fi < 4; ++fi) af[fi] = *(const bf16x8*)&lb[abase + fi * 512];
    asm volatile("s_waitcnt lgkmcnt(0)" ::: "memory");
    __builtin_amdgcn_sched_barrier(0);
    __builtin_amdgcn_s_setprio(1);
#pragma unroll
    for (int fi = 0; fi < 4; ++fi) {
      acc[fi][0] = __builtin_amdgcn_mfma_f32_16x16x32_bf16(af[fi], bf0, acc[fi][0], 0, 0, 0);
      acc[fi][1] = __builtin_amdgcn_mfma_f32_16x16x32_bf16(af[fi], bf1, acc[fi][1], 0, 0, 0);
    }
    __builtin_amdgcn_s_setprio(0);
#pragma unroll
    for (int fi = 0; fi < 4; ++fi) af[fi] = *(const bf16x8*)&lb[abase + (4 + fi) * 512];
    asm volatile("s_waitcnt lgkmcnt(0)" ::: "memory");
    __builtin_amdgcn_sched_barrier(0);
    __builtin_amdgcn_s_setprio(1);
#pragma unroll
    for (int fi = 0; fi < 4; ++fi) {
      acc[4 + fi][0] = __builtin_amdgcn_mfma_f32_16x16x32_bf16(af[fi], bf0, acc[4 + fi][0], 0, 0, 0);
      acc[4 + fi][1] = __builtin_amdgcn_mfma_f32_16x16x32_bf16(af[fi], bf1, acc[4 + fi][1], 0, 0, 0);
    }
    __builtin_amdgcn_s_setprio(0);
    asm volatile("s_waitcnt vmcnt(0)" ::: "memory");
    __builtin_amdgcn_s_barrier();
  }
#undef STG2

  // epilogue: D mapping col=lane&15, row=(lane>>4)*4+q
#pragma unroll
  for (int fi = 0; fi < 8; ++fi) {
#pragma unroll
    for (int fj = 0; fj < 2; ++fj) {
      const int col = n0 + wn * 32 + fj * 16 + r15;
      const int rowb = m0 + wm * 128 + fi * 16 + hi * 4;
      float cb = BIAS_ROW ? 0.0f : bias[col];
#pragma unroll
      for (int q = 0; q < 4; ++q) {
        const int row = rowb + q;
        float v = acc[fi][fj][q] + (BIAS_ROW ? bias[row] : cb);
        if constexpr (C_BF16) {
          ((unsigned short*)Cv)[(size_t)sC * z + (size_t)row * ldc + col] = f2bf(v);
        } else {
          ((float*)Cv)[(size_t)sC * z + (size_t)row * ldc + col] = v;
        }
      }
    }
  }
}

// ------------- chunked mixer scan -------------
__global__ __launch_bounds__(256) void scan_carry(const unsigned short* __restrict__ proj,
                                                  float* __restrict__ carry,
                                                  const float* __restrict__ mix_w,
                                                  const float* __restrict__ decay_v) {
  const int b = blockIdx.x >> 6;
  const int c = blockIdx.x & (NCH - 1);
  const int n0 = threadIdx.x * 4;
  const int h = n0 >> 7;
  const float d = fminf(fmaxf(decay_v[h], 0.9f), 1.0f);
  const float r = powf(d, 1.0f / (float)DECAYC);
  const bool colrep = h < (HEADS / 2);
  const u16x4* p = (const u16x4*)(proj + ((size_t)(b * SEQ + c * CHUNK)) * DIM + n0);
  const float* mw = mix_w + h * SEQ + c * CHUNK;
  float s0 = 0.f, s1 = 0.f, s2 = 0.f, s3 = 0.f;
#pragma unroll 8
  for (int t = 0; t < CHUNK; ++t) {
    u16x4 v = p[t * (DIM / 4)];
    float wi = colrep ? 1.0f : mw[t];
    s0 = s0 * r + bf2f(v[0]) * wi;
    s1 = s1 * r + bf2f(v[1]) * wi;
    s2 = s2 * r + bf2f(v[2]) * wi;
    s3 = s3 * r + bf2f(v[3]) * wi;
  }
  f32x4 out = {s0, s1, s2, s3};
  *(f32x4*)(carry + ((size_t)(b * NCH + c)) * DIM + n0) = out;
}

// Phase 2+3 fused: block (b,c) computes its own carry-in prefix from chunk sums
// (same ascending P = rL*P + carry[j] recurrence -> bit-identical), then replays.
__global__ __launch_bounds__(256) void scan_apply(const unsigned short* __restrict__ proj,
                                                  unsigned short* __restrict__ hidden,
                                                  const float* __restrict__ carry,
                                                  const float* __restrict__ mix_w,
                                                  const float* __restrict__ mix_b,
                                                  const float* __restrict__ decay_v) {
  const int b = blockIdx.x >> 6;
  const int c = blockIdx.x & (NCH - 1);
  const int n0 = threadIdx.x * 4;
  const int h = n0 >> 7;
  const float d = fminf(fmaxf(decay_v[h], 0.9f), 1.0f);
  const float r = powf(d, 1.0f / (float)DECAYC);
  const float rL = powf(r, (float)CHUNK);
  const bool colrep = h < (HEADS / 2);
  // in-block prefix over preceding chunk sums (L2-resident, 16B/iter)
  f32x4 P = {0.f, 0.f, 0.f, 0.f};
  for (int j = 0; j < c; ++j) {
    f32x4 cj = *(const f32x4*)(carry + ((size_t)(b * NCH + j)) * DIM + n0);
    P = P * rL + cj;
  }
  const size_t base = ((size_t)(b * SEQ + c * CHUNK)) * DIM + n0;
  const u16x4* p = (const u16x4*)(proj + base);
  u16x4* o = (u16x4*)(hidden + base);
  const float* mw = mix_w + h * SEQ + c * CHUNK;
  const float* mb = mix_b + h * SEQ + c * CHUNK;
  float s0 = P[0], s1 = P[1], s2 = P[2], s3 = P[3];
#pragma unroll 8
  for (int t = 0; t < CHUNK; ++t) {
    u16x4 v = p[t * (DIM / 4)];
    float wv = mw[t];
    float wi = colrep ? 1.0f : wv;
    float wo = colrep ? wv : 1.0f;
    float bb = mb[t];
    s0 = s0 * r + bf2f(v[0]) * wi;
    s1 = s1 * r + bf2f(v[1]) * wi;
    s2 = s2 * r + bf2f(v[2]) * wi;
    s3 = s3 * r + bf2f(v[3]) * wi;
    u16x4 ov;
    ov[0] = f2bf(s0 * wo + bb);
    ov[1] = f2bf(s1 * wo + bb);
    ov[2] = f2bf(s2 * wo + bb);
    ov[3] = f2bf(s3 * wo + bb);
    o[t * (DIM / 4)] = ov;
  }
}

extern "C" void kernel_launch(void* const* d_in, const int* in_sizes, int n_in,
                              void* d_out, int out_size, void* d_ws, size_t ws_size,
                              hipStream_t stream) {
  const float* x = (const float*)d_in[0];
  const float* proj_w = (const float*)d_in[1];
  const float* proj_b = (const float*)d_in[2];
  const float* mix_w = (const float*)d_in[3];
  const float* mix_b = (const float*)d_in[4];
  const float* decay_v = (const float*)d_in[5];
  const float* out_w = (const float*)d_in[6];
  const float* out_b = (const float*)d_in[7];

  char* ws = (char*)d_ws;
  unsigned short* xT = (unsigned short*)ws;                // 33.5 MB (B*T, E) bf16
  unsigned short* proj = (unsigned short*)(ws + 33554432); // 33.5 MB (B*T, N) bf16
  unsigned short* W1 = (unsigned short*)(ws + 67108864);   // 2 MB (dead after GEMM1)
  unsigned short* W2 = (unsigned short*)(ws + 69206016);   // 2 MB
  unsigned short* hidden = xT;                             // reuse: xT dead after GEMM1
  float* carryf = (float*)(ws + 67108864);                 // 2 MB, overlaps W1 (dead)

  const int NW = DIM * DIM;
  convertk2<<<dim3((NW + 255) / 256), 256, 0, stream>>>(proj_w, W1, out_w, W2, NW);
  transpose_x<<<dim3(16, 32, 8), 256, 0, stream>>>(x, xT);

  // GEMM1 (control arm, R6-VAR0): proj = xT . W1^T + proj_b
  gemm256<1, 0, 1><<<dim3(256), 512, 0, stream>>>(xT, W1, proj, proj_b, DIM, 0L, 0L);

  // chunked mixer scan (prefix fused into apply)
  scan_carry<<<dim3(8 * NCH), 256, 0, stream>>>(proj, carryf, mix_w, decay_v);
  scan_apply<<<dim3(8 * NCH), 256, 0, stream>>>(proj, hidden, carryf, mix_w, mix_b, decay_v);

  // GEMM2 (experiment arm, 256x128 2-blocks/CU): out[b] = W2 . hidden[b]^T + out_b
  gemm128n<0, 1, 2><<<dim3(512), 512, 0, stream>>>(W2, hidden, d_out, out_b, SEQ,
                                                   (long)SEQ * DIM, (long)DIM * SEQ);
}

// Round 9
// 135.399 us; speedup vs baseline: 1.0182x; 1.0182x over previous
//
#include <hip/hip_runtime.h>

#define DIM 1024
#define SEQ 2048
#define HID 128
#define HEADS 8
#define DECAYC 4
#define CHUNK 32
#define NCH (SEQ / CHUNK)  // 64
#define BK 64
#define NT (DIM / BK)      // 16 K-tiles

typedef __bf16 bf16x8 __attribute__((ext_vector_type(8)));
typedef float f32x4 __attribute__((ext_vector_type(4)));
typedef unsigned short u16x4 __attribute__((ext_vector_type(4)));
typedef unsigned short u16x8 __attribute__((ext_vector_type(8)));

__device__ __forceinline__ unsigned short f2bf(float f) {
  union { float f; unsigned u; } v; v.f = f;
  unsigned r = v.u + 0x7fffu + ((v.u >> 16) & 1u);
  return (unsigned short)(r >> 16);
}
__device__ __forceinline__ float bf2f(unsigned short u) {
  union { unsigned u; float f; } v; v.u = ((unsigned)u) << 16;
  return v.f;
}

typedef __attribute__((address_space(1))) const unsigned int* g_u32p;
typedef __attribute__((address_space(3))) unsigned int* l_u32p;

__device__ __forceinline__ void async_ld16(const unsigned short* g, unsigned short* l) {
  __builtin_amdgcn_global_load_lds((g_u32p)g, (l_u32p)l, 16, 0, 0);
}

// ---------------- fp32 -> bf16 convert (both weights, one launch) ----------------
__global__ void convertk2(const float* __restrict__ in0, unsigned short* __restrict__ out0,
                          const float* __restrict__ in1, unsigned short* __restrict__ out1,
                          int n) {
  int i = blockIdx.x * 256 + threadIdx.x;
  if (i < n) {
    out0[i] = f2bf(in0[i]);
    out1[i] = f2bf(in1[i]);
  }
}

// ------------- GEMM1 with fused x-transpose -------------
// proj[(b,t)][n] = sum_e x[b][e][t] * W1[n][e] + proj_b[n]
// grid 256 = 64 m-tiles x 4 n-tiles; 8 waves (2M x 4N); BK=64, one barrier/tile.
// LDS 128KB: [2 buf][A 32KB | B 32KB], 128B rows, swizzle byte ^= ((row>>2)&7)<<4.
// A staged via reg-transpose (8 f32x4 loads -> f2bf -> 4 ds_write_b128 per wave);
// B staged via global_load_lds with inverse-swizzled source.
__global__ __launch_bounds__(512, 2) void gemm1f(const float* __restrict__ x,
                                                 const unsigned short* __restrict__ W1,
                                                 unsigned short* __restrict__ proj,
                                                 const float* __restrict__ bias) {
  __shared__ unsigned short lds[65536];  // 128 KiB

  const int m0 = (blockIdx.x >> 2) * 256;
  const int n0 = (blockIdx.x & 3) * 256;
  const int b = m0 >> 11;       // batch
  const int t0 = m0 & 2047;     // t offset within batch

  const int tid = threadIdx.x;
  const int lane = tid & 63;
  const int w = tid >> 6;
  const int wm = w >> 2;  // 0..1
  const int wn = w & 3;   // 0..3

  // ---- B staging sources (inverse swz128: byte ^= ((byte>>9)&7)<<4) ----
  const unsigned short* spB[4];
#pragma unroll
  for (int j = 0; j < 4; ++j) {
    int c = j * 8192 + tid * 16;             // linear dest byte in 32KB B region
    int cs = c ^ (((c >> 9) & 7) << 4);      // involution
    spB[j] = W1 + (size_t)(n0 + (cs >> 7)) * DIM + ((cs & 127) >> 1);
  }

  // ---- A (x) source: wave w owns e-chunk w*8..w*8+7; lane owns t = 4*lane..+3 ----
  const float* xbase = x + ((size_t)b * DIM + w * 8) * SEQ + t0 + lane * 4;

  // A ds_write byte (within A region), row t=4*lane+tt: swz bits = lane&7
  const int awbyte = (lane * 4) * 128 + ((w * 16) ^ ((lane & 7) << 4));

  // ---- fragment read offsets (swizzled, ushort idx) ----
  const int r15 = lane & 15;
  const int hi = lane >> 4;
  int aoff[8][2], boff[4][2];
#pragma unroll
  for (int fi = 0; fi < 8; ++fi) {
    int t = wm * 128 + fi * 16 + r15;
#pragma unroll
    for (int ks = 0; ks < 2; ++ks)
      aoff[fi][ks] = ((t * 128 + ks * 64 + hi * 16) ^ (((t >> 2) & 7) << 4)) >> 1;
  }
#pragma unroll
  for (int fj = 0; fj < 4; ++fj) {
    int n = wn * 64 + fj * 16 + r15;
#pragma unroll
    for (int ks = 0; ks < 2; ++ks)
      boff[fj][ks] = 16384 + (((n * 128 + ks * 64 + hi * 16) ^ (((n >> 2) & 7) << 4)) >> 1);
  }

  f32x4 acc[8][4] = {};
  f32x4 ar[8];

#define ALOAD(tgt)                                                             \
  _Pragma("unroll") for (int ee = 0; ee < 8; ++ee)                             \
      ar[ee] = *(const f32x4*)(xbase + ((size_t)(tgt) * BK + ee) * SEQ);

#define BDMA(dd, tgt)                                                          \
  _Pragma("unroll") for (int j = 0; j < 4; ++j)                                \
      async_ld16(spB[j] + (size_t)(tgt) * BK,                                  \
                 (unsigned short*)lds + (dd) * 32768 + 16384 + j * 4096 + tid * 8);

#define AWRITE(dd)                                                             \
  {                                                                            \
    char* ab = (char*)lds + (dd) * 65536;                                      \
    _Pragma("unroll") for (int tt = 0; tt < 4; ++tt) {                         \
      u16x8 hv;                                                                \
      _Pragma("unroll") for (int ee = 0; ee < 8; ++ee) hv[ee] = f2bf(ar[ee][tt]); \
      *(u16x8*)(ab + awbyte + tt * 128) = hv;                                  \
    }                                                                          \
  }

  // prologue: stage tile 0 into buf 0
  ALOAD(0);
  BDMA(0, 0);
  asm volatile("s_waitcnt vmcnt(4)" ::: "memory");  // A loads done
  AWRITE(0);
  asm volatile("s_waitcnt vmcnt(0) lgkmcnt(0)" ::: "memory");
  __builtin_amdgcn_s_barrier();

#pragma unroll
  for (int t = 0; t < NT; ++t) {
    const int d = t & 1;
    const unsigned short* lb = (const unsigned short*)lds + d * 32768;
    if (t + 1 < NT) {
      ALOAD(t + 1);
      BDMA(d ^ 1, t + 1);
    }
    // 4 sub-phases: (ks, fi-half); B frags re-read per ks, A per half
#pragma unroll
    for (int ks = 0; ks < 2; ++ks) {
      bf16x8 bfr[4];
#pragma unroll
      for (int j = 0; j < 4; ++j) bfr[j] = *(const bf16x8*)&lb[boff[j][ks]];
#pragma unroll
      for (int Hh = 0; Hh < 2; ++Hh) {
        bf16x8 af[4];
#pragma unroll
        for (int i = 0; i < 4; ++i) af[i] = *(const bf16x8*)&lb[aoff[Hh * 4 + i][ks]];
        asm volatile("s_waitcnt lgkmcnt(0)" ::: "memory");
        __builtin_amdgcn_sched_barrier(0);
        __builtin_amdgcn_s_setprio(1);
#pragma unroll
        for (int i = 0; i < 4; ++i)
#pragma unroll
          for (int j = 0; j < 4; ++j)
            acc[Hh * 4 + i][j] = __builtin_amdgcn_mfma_f32_16x16x32_bf16(
                af[i], bfr[j], acc[Hh * 4 + i][j], 0, 0, 0);
        __builtin_amdgcn_s_setprio(0);
      }
    }
    if (t + 1 < NT) {
      asm volatile("s_waitcnt vmcnt(4)" ::: "memory");  // A reg-loads done (B DMA may fly)
      AWRITE(d ^ 1);
    }
    asm volatile("s_waitcnt vmcnt(0) lgkmcnt(0)" ::: "memory");
    __builtin_amdgcn_s_barrier();
  }
#undef ALOAD
#undef BDMA
#undef AWRITE

  // epilogue: D mapping col=lane&15, row=(lane>>4)*4+q
  const int or0 = hi * 4;
#pragma unroll
  for (int fi = 0; fi < 8; ++fi) {
#pragma unroll
    for (int fj = 0; fj < 4; ++fj) {
      const int col = n0 + wn * 64 + fj * 16 + r15;
      const int rowb = m0 + wm * 128 + fi * 16 + or0;
      float cb = bias[col];
#pragma unroll
      for (int q = 0; q < 4; ++q) {
        const int row = rowb + q;
        proj[(size_t)row * DIM + col] = f2bf(acc[fi][fj][q] + cb);
      }
    }
  }
}

// ------------- 256x256 8-phase pipelined NT GEMM (R7 control, GEMM2) -------------
template <int C_BF16, int BIAS_ROW, int MODE>
__global__ __launch_bounds__(512, 2) void gemm256(const unsigned short* __restrict__ A,
                                                  const unsigned short* __restrict__ B,
                                                  void* __restrict__ Cv,
                                                  const float* __restrict__ bias,
                                                  int ldc, long sB, long sC) {
  __shared__ unsigned short lds[65536];  // 128 KiB

  int m0, n0, z;
  if constexpr (MODE == 1) {
    m0 = (blockIdx.x >> 2) * 256;
    n0 = (blockIdx.x & 3) * 256;
    z = 0;
  } else {
    z = blockIdx.x >> 5;
    m0 = ((blockIdx.x >> 3) & 3) * 256;
    n0 = (blockIdx.x & 7) * 256;
  }
  B += (size_t)sB * z;

  const int tid = threadIdx.x;
  const int lane = tid & 63;
  const int w = tid >> 6;
  const int wm = w >> 2;
  const int wn = w & 3;

  const unsigned short* sp[2][2][2];
#pragma unroll
  for (int j = 0; j < 2; ++j) {
    int c = (w * 2 + j) * 1024 + lane * 16;
    int cs = c ^ (((c >> 7) & 3) << 4);
    int row = cs >> 6;
    int colel = (cs & 63) >> 1;
#pragma unroll
    for (int kh = 0; kh < 2; ++kh) {
      sp[0][kh][j] = A + (size_t)(m0 + row) * DIM + kh * 32 + colel;
      sp[1][kh][j] = B + (size_t)(n0 + row) * DIM + kh * 32 + colel;
    }
  }

  const int r15 = lane & 15;
  const int hi = lane >> 4;
  const int rsw = ((r15 >> 1) & 3) << 4;
  int aoff[8][2], boff[4][2];
#pragma unroll
  for (int fi = 0; fi < 8; ++fi) {
    int byte = ((wm * 128 + fi * 16 + r15) * 64 + hi * 16) ^ rsw;
#pragma unroll
    for (int ks = 0; ks < 2; ++ks) aoff[fi][ks] = ks * 8192 + (byte >> 1);
  }
#pragma unroll
  for (int fj = 0; fj < 4; ++fj) {
    int byte = ((wn * 64 + fj * 16 + r15) * 64 + hi * 16) ^ rsw;
#pragma unroll
    for (int ks = 0; ks < 2; ++ks) boff[fj][ks] = 16384 + ks * 8192 + (byte >> 1);
  }

  f32x4 acc[8][4] = {};

#define STG(dd, op, kh, tgt)                                                    \
  if ((tgt) < NT) {                                                             \
    unsigned short* dst_ = (unsigned short*)lds + (dd) * 32768 + (op) * 16384 + \
                           (kh) * 8192 + w * 1024;                              \
    async_ld16(sp[op][kh][0] + (tgt) * BK, dst_);                               \
    async_ld16(sp[op][kh][1] + (tgt) * BK, dst_ + 512);                         \
  }

#define PHASE(H_, KS_, MIDBAR, STAGE_STMT)                                      \
  {                                                                             \
    bf16x8 af[4], bfr[4];                                                       \
    _Pragma("unroll") for (int i = 0; i < 4; ++i)                               \
        af[i] = *(const bf16x8*)&lb[aoff[(H_) * 4 + i][KS_]];                   \
    _Pragma("unroll") for (int j = 0; j < 4; ++j)                               \
        bfr[j] = *(const bf16x8*)&lb[boff[j][KS_]];                             \
    STAGE_STMT;                                                                 \
    if (MIDBAR) __builtin_amdgcn_s_barrier();                                   \
    asm volatile("s_waitcnt lgkmcnt(0)" ::: "memory");                          \
    __builtin_amdgcn_sched_barrier(0);                                          \
    __builtin_amdgcn_s_setprio(1);                                              \
    _Pragma("unroll") for (int i = 0; i < 4; ++i)                               \
      _Pragma("unroll") for (int j = 0; j < 4; ++j)                             \
        acc[(H_) * 4 + i][j] = __builtin_amdgcn_mfma_f32_16x16x32_bf16(         \
            af[i], bfr[j], acc[(H_) * 4 + i][j], 0, 0, 0);                      \
    __builtin_amdgcn_s_setprio(0);                                              \
    __builtin_amdgcn_s_barrier();                                               \
  }

  STG(0, 0, 0, 0); STG(0, 1, 0, 0); STG(0, 0, 1, 0); STG(0, 1, 1, 0);
  STG(1, 0, 0, 1); STG(1, 1, 0, 1);

#pragma unroll
  for (int t = 0; t < NT; ++t) {
    const int d = t & 1;
    const unsigned short* lb = (const unsigned short*)lds + d * 32768;
    if (t == NT - 1) {
      asm volatile("s_waitcnt vmcnt(0)" ::: "memory");
    } else {
      asm volatile("s_waitcnt vmcnt(4)" ::: "memory");
    }
    __builtin_amdgcn_s_barrier();
    PHASE(0, 0, 0, STG(d ^ 1, 0, 1, t + 1));
    PHASE(1, 0, 1, STG(d ^ 1, 1, 1, t + 1));
    PHASE(0, 1, 1, STG(d, 0, 0, t + 2));
    PHASE(1, 1, 1, STG(d, 1, 0, t + 2));
  }
#undef PHASE
#undef STG

  const int or0 = hi * 4;
#pragma unroll
  for (int fi = 0; fi < 8; ++fi) {
#pragma unroll
    for (int fj = 0; fj < 4; ++fj) {
      const int col = n0 + wn * 64 + fj * 16 + r15;
      const int rowb = m0 + wm * 128 + fi * 16 + or0;
      float cb = BIAS_ROW ? 0.0f : bias[col];
#pragma unroll
      for (int q = 0; q < 4; ++q) {
        const int row = rowb + q;
        float v = acc[fi][fj][q] + (BIAS_ROW ? bias[row] : cb);
        if constexpr (C_BF16) {
          ((unsigned short*)Cv)[(size_t)sC * z + (size_t)row * ldc + col] = f2bf(v);
        } else {
          ((float*)Cv)[(size_t)sC * z + (size_t)row * ldc + col] = v;
        }
      }
    }
  }
}

// ------------- chunked mixer scan (3-kernel, R7-proven) -------------
__global__ __launch_bounds__(256) void scan_carry(const unsigned short* __restrict__ proj,
                                                  float* __restrict__ carry,
                                                  const float* __restrict__ mix_w,
                                                  const float* __restrict__ decay_v) {
  const int b = blockIdx.x >> 6;
  const int c = blockIdx.x & (NCH - 1);
  const int n0 = threadIdx.x * 4;
  const int h = n0 >> 7;
  const float d = fminf(fmaxf(decay_v[h], 0.9f), 1.0f);
  const float r = powf(d, 1.0f / (float)DECAYC);
  const bool colrep = h < (HEADS / 2);
  const u16x4* p = (const u16x4*)(proj + ((size_t)(b * SEQ + c * CHUNK)) * DIM + n0);
  const float* mw = mix_w + h * SEQ + c * CHUNK;
  float s0 = 0.f, s1 = 0.f, s2 = 0.f, s3 = 0.f;
#pragma unroll 8
  for (int t = 0; t < CHUNK; ++t) {
    u16x4 v = p[t * (DIM / 4)];
    float wi = colrep ? 1.0f : mw[t];
    s0 = s0 * r + bf2f(v[0]) * wi;
    s1 = s1 * r + bf2f(v[1]) * wi;
    s2 = s2 * r + bf2f(v[2]) * wi;
    s3 = s3 * r + bf2f(v[3]) * wi;
  }
  f32x4 out = {s0, s1, s2, s3};
  *(f32x4*)(carry + ((size_t)(b * NCH + c)) * DIM + n0) = out;
}

__global__ __launch_bounds__(256) void scan_prefix(float* __restrict__ carry,
                                                   const float* __restrict__ decay_v) {
  const int idx = blockIdx.x * 256 + threadIdx.x;
  const int b = idx >> 10;
  const int n = idx & 1023;
  const int h = n >> 7;
  const float d = fminf(fmaxf(decay_v[h], 0.9f), 1.0f);
  const float r = powf(d, 1.0f / (float)DECAYC);
  const float rL = powf(r, (float)CHUNK);
  float P = 0.0f;
  for (int c = 0; c < NCH; ++c) {
    float* p = carry + ((size_t)(b * NCH + c)) * DIM + n;
    float cc = *p;
    *p = P;
    P = rL * P + cc;
  }
}

__global__ __launch_bounds__(256) void scan_apply(const unsigned short* __restrict__ proj,
                                                  unsigned short* __restrict__ hidden,
                                                  const float* __restrict__ carry,
                                                  const float* __restrict__ mix_w,
                                                  const float* __restrict__ mix_b,
                                                  const float* __restrict__ decay_v) {
  const int b = blockIdx.x >> 6;
  const int c = blockIdx.x & (NCH - 1);
  const int n0 = threadIdx.x * 4;
  const int h = n0 >> 7;
  const float d = fminf(fmaxf(decay_v[h], 0.9f), 1.0f);
  const float r = powf(d, 1.0f / (float)DECAYC);
  const bool colrep = h < (HEADS / 2);
  const size_t base = ((size_t)(b * SEQ + c * CHUNK)) * DIM + n0;
  const u16x4* p = (const u16x4*)(proj + base);
  u16x4* o = (u16x4*)(hidden + base);
  const float* mw = mix_w + h * SEQ + c * CHUNK;
  const float* mb = mix_b + h * SEQ + c * CHUNK;
  f32x4 ci = *(const f32x4*)(carry + ((size_t)(b * NCH + c)) * DIM + n0);
  float s0 = ci[0], s1 = ci[1], s2 = ci[2], s3 = ci[3];
#pragma unroll 8
  for (int t = 0; t < CHUNK; ++t) {
    u16x4 v = p[t * (DIM / 4)];
    float wv = mw[t];
    float wi = colrep ? 1.0f : wv;
    float wo = colrep ? wv : 1.0f;
    float bb = mb[t];
    s0 = s0 * r + bf2f(v[0]) * wi;
    s1 = s1 * r + bf2f(v[1]) * wi;
    s2 = s2 * r + bf2f(v[2]) * wi;
    s3 = s3 * r + bf2f(v[3]) * wi;
    u16x4 ov;
    ov[0] = f2bf(s0 * wo + bb);
    ov[1] = f2bf(s1 * wo + bb);
    ov[2] = f2bf(s2 * wo + bb);
    ov[3] = f2bf(s3 * wo + bb);
    o[t * (DIM / 4)] = ov;
  }
}

extern "C" void kernel_launch(void* const* d_in, const int* in_sizes, int n_in,
                              void* d_out, int out_size, void* d_ws, size_t ws_size,
                              hipStream_t stream) {
  const float* x = (const float*)d_in[0];
  const float* proj_w = (const float*)d_in[1];
  const float* proj_b = (const float*)d_in[2];
  const float* mix_w = (const float*)d_in[3];
  const float* mix_b = (const float*)d_in[4];
  const float* decay_v = (const float*)d_in[5];
  const float* out_w = (const float*)d_in[6];
  const float* out_b = (const float*)d_in[7];

  char* ws = (char*)d_ws;
  unsigned short* hidden = (unsigned short*)ws;            // 33.5 MB (B*T, N) bf16
  unsigned short* proj = (unsigned short*)(ws + 33554432); // 33.5 MB (B*T, N) bf16
  unsigned short* W1 = (unsigned short*)(ws + 67108864);   // 2 MB (dead after GEMM1)
  unsigned short* W2 = (unsigned short*)(ws + 69206016);   // 2 MB
  float* carryf = (float*)(ws + 67108864);                 // 2 MB, overlaps W1 (dead)

  const int NW = DIM * DIM;
  convertk2<<<dim3((NW + 255) / 256), 256, 0, stream>>>(proj_w, W1, out_w, W2, NW);

  // GEMM1 (fused transpose): proj = x^T . W1^T + proj_b  (reads x directly)
  gemm1f<<<dim3(256), 512, 0, stream>>>(x, W1, proj, proj_b);

  // chunked mixer scan (3-kernel)
  scan_carry<<<dim3(8 * NCH), 256, 0, stream>>>(proj, carryf, mix_w, decay_v);
  scan_prefix<<<dim3(8192 / 256), 256, 0, stream>>>(carryf, decay_v);
  scan_apply<<<dim3(8 * NCH), 256, 0, stream>>>(proj, hidden, carryf, mix_w, mix_b, decay_v);

  // GEMM2 (control arm, R7-proven): out[b] = W2 . hidden[b]^T + out_b
  gemm256<0, 1, 2><<<dim3(256), 512, 0, stream>>>(W2, hidden, d_out, out_b, SEQ,
                                                  (long)SEQ * DIM, (long)DIM * SEQ);
}

// Round 10
// 124.990 us; speedup vs baseline: 1.1030x; 1.0833x over previous
//
#include <hip/hip_runtime.h>

#define DIM 1024
#define SEQ 2048
#define HID 128
#define HEADS 8
#define DECAYC 4
#define CHUNK 32
#define NCH (SEQ / CHUNK)  // 64
#define BK 64
#define NT (DIM / BK)      // 16 K-tiles

typedef __bf16 bf16x8 __attribute__((ext_vector_type(8)));
typedef float f32x4 __attribute__((ext_vector_type(4)));
typedef unsigned short u16x4 __attribute__((ext_vector_type(4)));
typedef unsigned short u16x8 __attribute__((ext_vector_type(8)));

__device__ __forceinline__ unsigned short f2bf(float f) {
  union { float f; unsigned u; } v; v.f = f;
  unsigned r = v.u + 0x7fffu + ((v.u >> 16) & 1u);
  return (unsigned short)(r >> 16);
}
__device__ __forceinline__ float bf2f(unsigned short u) {
  union { unsigned u; float f; } v; v.u = ((unsigned)u) << 16;
  return v.f;
}

typedef __attribute__((address_space(1))) const unsigned int* g_u32p;
typedef __attribute__((address_space(3))) unsigned int* l_u32p;

__device__ __forceinline__ void async_ld16(const unsigned short* g, unsigned short* l) {
  __builtin_amdgcn_global_load_lds((g_u32p)g, (l_u32p)l, 16, 0, 0);
}

// ------------- prep: x transpose (blocks 0..4095) + weight converts (4096..6143) -------------
__global__ __launch_bounds__(256) void prep(const float* __restrict__ x,
                                            unsigned short* __restrict__ xT,
                                            const float* __restrict__ w1f,
                                            unsigned short* __restrict__ W1,
                                            const float* __restrict__ w2f,
                                            unsigned short* __restrict__ W2) {
  const int bid = blockIdx.x;
  if (bid < 4096) {
    // transpose x (B,E,T) f32 -> xT (B,T,E) bf16
    __shared__ float tile[64][65];
    const int b = bid >> 9;
    const int rem = bid & 511;
    const int t0 = (rem >> 4) * 64;
    const int e0 = (rem & 15) * 64;
    const int tr = threadIdx.x >> 6;
    const int tc = threadIdx.x & 63;
    const float* xp = x + ((size_t)b * DIM + e0) * SEQ + t0;
#pragma unroll
    for (int i = 0; i < 16; ++i) {
      int e = i * 4 + tr;
      tile[e][tc] = xp[(size_t)e * SEQ + tc];
    }
    __syncthreads();
    unsigned short* op = xT + ((size_t)b * SEQ + t0) * DIM + e0;
    const int tq = threadIdx.x >> 4;        // 0..15
    const int e4 = (threadIdx.x & 15) * 4;  // 0..60
#pragma unroll
    for (int i = 0; i < 4; ++i) {
      int t = i * 16 + tq;
      u16x4 ov;
      ov[0] = f2bf(tile[e4 + 0][t]);
      ov[1] = f2bf(tile[e4 + 1][t]);
      ov[2] = f2bf(tile[e4 + 2][t]);
      ov[3] = f2bf(tile[e4 + 3][t]);
      *(u16x4*)&op[(size_t)t * DIM + e4] = ov;
    }
  } else {
    const int wid = bid - 4096;             // 0..2047
    const float* src = (wid < 1024) ? w1f : w2f;
    unsigned short* dst = (wid < 1024) ? W1 : W2;
    const int i = (wid & 1023) * 1024 + threadIdx.x * 4;
    f32x4 v = *(const f32x4*)&src[i];
    u16x4 ov;
    ov[0] = f2bf(v[0]);
    ov[1] = f2bf(v[1]);
    ov[2] = f2bf(v[2]);
    ov[3] = f2bf(v[3]);
    *(u16x4*)&dst[i] = ov;
  }
}

// ------------- 256x256 8-phase pipelined NT GEMM (R7-proven) -------------
template <int C_BF16, int BIAS_ROW, int MODE>
__global__ __launch_bounds__(512, 2) void gemm256(const unsigned short* __restrict__ A,
                                                  const unsigned short* __restrict__ B,
                                                  void* __restrict__ Cv,
                                                  const float* __restrict__ bias,
                                                  int ldc, long sB, long sC) {
  __shared__ unsigned short lds[65536];  // 128 KiB

  int m0, n0, z;
  if constexpr (MODE == 1) {
    m0 = (blockIdx.x >> 2) * 256;
    n0 = (blockIdx.x & 3) * 256;
    z = 0;
  } else {
    z = blockIdx.x >> 5;
    m0 = ((blockIdx.x >> 3) & 3) * 256;
    n0 = (blockIdx.x & 7) * 256;
  }
  B += (size_t)sB * z;

  const int tid = threadIdx.x;
  const int lane = tid & 63;
  const int w = tid >> 6;
  const int wm = w >> 2;
  const int wn = w & 3;

  const unsigned short* sp[2][2][2];
#pragma unroll
  for (int j = 0; j < 2; ++j) {
    int c = (w * 2 + j) * 1024 + lane * 16;
    int cs = c ^ (((c >> 7) & 3) << 4);
    int row = cs >> 6;
    int colel = (cs & 63) >> 1;
#pragma unroll
    for (int kh = 0; kh < 2; ++kh) {
      sp[0][kh][j] = A + (size_t)(m0 + row) * DIM + kh * 32 + colel;
      sp[1][kh][j] = B + (size_t)(n0 + row) * DIM + kh * 32 + colel;
    }
  }

  const int r15 = lane & 15;
  const int hi = lane >> 4;
  const int rsw = ((r15 >> 1) & 3) << 4;
  int aoff[8][2], boff[4][2];
#pragma unroll
  for (int fi = 0; fi < 8; ++fi) {
    int byte = ((wm * 128 + fi * 16 + r15) * 64 + hi * 16) ^ rsw;
#pragma unroll
    for (int ks = 0; ks < 2; ++ks) aoff[fi][ks] = ks * 8192 + (byte >> 1);
  }
#pragma unroll
  for (int fj = 0; fj < 4; ++fj) {
    int byte = ((wn * 64 + fj * 16 + r15) * 64 + hi * 16) ^ rsw;
#pragma unroll
    for (int ks = 0; ks < 2; ++ks) boff[fj][ks] = 16384 + ks * 8192 + (byte >> 1);
  }

  f32x4 acc[8][4] = {};

#define STG(dd, op, kh, tgt)                                                    \
  if ((tgt) < NT) {                                                             \
    unsigned short* dst_ = (unsigned short*)lds + (dd) * 32768 + (op) * 16384 + \
                           (kh) * 8192 + w * 1024;                              \
    async_ld16(sp[op][kh][0] + (tgt) * BK, dst_);                               \
    async_ld16(sp[op][kh][1] + (tgt) * BK, dst_ + 512);                         \
  }

#define PHASE(H_, KS_, MIDBAR, STAGE_STMT)                                      \
  {                                                                             \
    bf16x8 af[4], bfr[4];                                                       \
    _Pragma("unroll") for (int i = 0; i < 4; ++i)                               \
        af[i] = *(const bf16x8*)&lb[aoff[(H_) * 4 + i][KS_]];                   \
    _Pragma("unroll") for (int j = 0; j < 4; ++j)                               \
        bfr[j] = *(const bf16x8*)&lb[boff[j][KS_]];                             \
    STAGE_STMT;                                                                 \
    if (MIDBAR) __builtin_amdgcn_s_barrier();                                   \
    asm volatile("s_waitcnt lgkmcnt(0)" ::: "memory");                          \
    __builtin_amdgcn_sched_barrier(0);                                          \
    __builtin_amdgcn_s_setprio(1);                                              \
    _Pragma("unroll") for (int i = 0; i < 4; ++i)                               \
      _Pragma("unroll") for (int j = 0; j < 4; ++j)                             \
        acc[(H_) * 4 + i][j] = __builtin_amdgcn_mfma_f32_16x16x32_bf16(         \
            af[i], bfr[j], acc[(H_) * 4 + i][j], 0, 0, 0);                      \
    __builtin_amdgcn_s_setprio(0);                                              \
    __builtin_amdgcn_s_barrier();                                               \
  }

  STG(0, 0, 0, 0); STG(0, 1, 0, 0); STG(0, 0, 1, 0); STG(0, 1, 1, 0);
  STG(1, 0, 0, 1); STG(1, 1, 0, 1);

#pragma unroll
  for (int t = 0; t < NT; ++t) {
    const int d = t & 1;
    const unsigned short* lb = (const unsigned short*)lds + d * 32768;
    if (t == NT - 1) {
      asm volatile("s_waitcnt vmcnt(0)" ::: "memory");
    } else {
      asm volatile("s_waitcnt vmcnt(4)" ::: "memory");
    }
    __builtin_amdgcn_s_barrier();
    PHASE(0, 0, 0, STG(d ^ 1, 0, 1, t + 1));
    PHASE(1, 0, 1, STG(d ^ 1, 1, 1, t + 1));
    PHASE(0, 1, 1, STG(d, 0, 0, t + 2));
    PHASE(1, 1, 1, STG(d, 1, 0, t + 2));
  }
#undef PHASE
#undef STG

  const int or0 = hi * 4;
#pragma unroll
  for (int fi = 0; fi < 8; ++fi) {
#pragma unroll
    for (int fj = 0; fj < 4; ++fj) {
      const int col = n0 + wn * 64 + fj * 16 + r15;
      const int rowb = m0 + wm * 128 + fi * 16 + or0;
      float cb = BIAS_ROW ? 0.0f : bias[col];
#pragma unroll
      for (int q = 0; q < 4; ++q) {
        const int row = rowb + q;
        float v = acc[fi][fj][q] + (BIAS_ROW ? bias[row] : cb);
        if constexpr (C_BF16) {
          ((unsigned short*)Cv)[(size_t)sC * z + (size_t)row * ldc + col] = f2bf(v);
        } else {
          ((float*)Cv)[(size_t)sC * z + (size_t)row * ldc + col] = v;
        }
      }
    }
  }
}

// ------------- chunked mixer scan (u16x8 vectorized: 128 thr x 8 ch) -------------
__global__ __launch_bounds__(128) void scan_carry(const unsigned short* __restrict__ proj,
                                                  float* __restrict__ carry,
                                                  const float* __restrict__ mix_w,
                                                  const float* __restrict__ decay_v) {
  const int b = blockIdx.x >> 6;
  const int c = blockIdx.x & (NCH - 1);
  const int n0 = threadIdx.x * 8;
  const int h = n0 >> 7;
  const float d = fminf(fmaxf(decay_v[h], 0.9f), 1.0f);
  const float r = powf(d, 1.0f / (float)DECAYC);
  const bool colrep = h < (HEADS / 2);
  const u16x8* p = (const u16x8*)(proj + ((size_t)(b * SEQ + c * CHUNK)) * DIM + n0);
  const float* mw = mix_w + h * SEQ + c * CHUNK;
  float s[8] = {};
#pragma unroll 8
  for (int t = 0; t < CHUNK; ++t) {
    u16x8 v = p[t * (DIM / 8)];
    float wi = colrep ? 1.0f : mw[t];
#pragma unroll
    for (int e = 0; e < 8; ++e) s[e] = s[e] * r + bf2f(v[e]) * wi;
  }
  float* cp = carry + ((size_t)(b * NCH + c)) * DIM + n0;
  *(f32x4*)cp = f32x4{s[0], s[1], s[2], s[3]};
  *(f32x4*)(cp + 4) = f32x4{s[4], s[5], s[6], s[7]};
}

__global__ __launch_bounds__(256) void scan_prefix(float* __restrict__ carry,
                                                   const float* __restrict__ decay_v) {
  const int idx = blockIdx.x * 256 + threadIdx.x;
  const int b = idx >> 10;
  const int n = idx & 1023;
  const int h = n >> 7;
  const float d = fminf(fmaxf(decay_v[h], 0.9f), 1.0f);
  const float r = powf(d, 1.0f / (float)DECAYC);
  const float rL = powf(r, (float)CHUNK);
  float P = 0.0f;
  for (int c = 0; c < NCH; ++c) {
    float* p = carry + ((size_t)(b * NCH + c)) * DIM + n;
    float cc = *p;
    *p = P;
    P = rL * P + cc;
  }
}

__global__ __launch_bounds__(128) void scan_apply(const unsigned short* __restrict__ proj,
                                                  unsigned short* __restrict__ hidden,
                                                  const float* __restrict__ carry,
                                                  const float* __restrict__ mix_w,
                                                  const float* __restrict__ mix_b,
                                                  const float* __restrict__ decay_v) {
  const int b = blockIdx.x >> 6;
  const int c = blockIdx.x & (NCH - 1);
  const int n0 = threadIdx.x * 8;
  const int h = n0 >> 7;
  const float d = fminf(fmaxf(decay_v[h], 0.9f), 1.0f);
  const float r = powf(d, 1.0f / (float)DECAYC);
  const bool colrep = h < (HEADS / 2);
  const size_t base = ((size_t)(b * SEQ + c * CHUNK)) * DIM + n0;
  const u16x8* p = (const u16x8*)(proj + base);
  u16x8* o = (u16x8*)(hidden + base);
  const float* mw = mix_w + h * SEQ + c * CHUNK;
  const float* mb = mix_b + h * SEQ + c * CHUNK;
  const float* cp = carry + ((size_t)(b * NCH + c)) * DIM + n0;
  float s[8];
  {
    f32x4 c0 = *(const f32x4*)cp;
    f32x4 c1 = *(const f32x4*)(cp + 4);
#pragma unroll
    for (int e = 0; e < 4; ++e) { s[e] = c0[e]; s[4 + e] = c1[e]; }
  }
#pragma unroll 8
  for (int t = 0; t < CHUNK; ++t) {
    u16x8 v = p[t * (DIM / 8)];
    float wv = mw[t];
    float wi = colrep ? 1.0f : wv;
    float wo = colrep ? wv : 1.0f;
    float bb = mb[t];
    u16x8 ov;
#pragma unroll
    for (int e = 0; e < 8; ++e) {
      s[e] = s[e] * r + bf2f(v[e]) * wi;
      ov[e] = f2bf(s[e] * wo + bb);
    }
    o[t * (DIM / 8)] = ov;
  }
}

extern "C" void kernel_launch(void* const* d_in, const int* in_sizes, int n_in,
                              void* d_out, int out_size, void* d_ws, size_t ws_size,
                              hipStream_t stream) {
  const float* x = (const float*)d_in[0];
  const float* proj_w = (const float*)d_in[1];
  const float* proj_b = (const float*)d_in[2];
  const float* mix_w = (const float*)d_in[3];
  const float* mix_b = (const float*)d_in[4];
  const float* decay_v = (const float*)d_in[5];
  const float* out_w = (const float*)d_in[6];
  const float* out_b = (const float*)d_in[7];

  char* ws = (char*)d_ws;
  unsigned short* xT = (unsigned short*)ws;                // 33.5 MB (B*T, E) bf16
  unsigned short* proj = (unsigned short*)(ws + 33554432); // 33.5 MB (B*T, N) bf16
  unsigned short* W1 = (unsigned short*)(ws + 67108864);   // 2 MB (dead after GEMM1)
  unsigned short* W2 = (unsigned short*)(ws + 69206016);   // 2 MB
  unsigned short* hidden = xT;                             // reuse: xT dead after GEMM1
  float* carryf = (float*)(ws + 67108864);                 // 2 MB, overlaps W1 (dead)

  // prep: transpose x + convert both weights in one launch
  prep<<<dim3(6144), 256, 0, stream>>>(x, xT, proj_w, W1, out_w, W2);

  // GEMM1: proj = xT . W1^T + proj_b
  gemm256<1, 0, 1><<<dim3(256), 512, 0, stream>>>(xT, W1, proj, proj_b, DIM, 0L, 0L);

  // chunked mixer scan
  scan_carry<<<dim3(8 * NCH), 128, 0, stream>>>(proj, carryf, mix_w, decay_v);
  scan_prefix<<<dim3(8192 / 256), 256, 0, stream>>>(carryf, decay_v);
  scan_apply<<<dim3(8 * NCH), 128, 0, stream>>>(proj, hidden, carryf, mix_w, mix_b, decay_v);

  // GEMM2: out[b] = W2 . hidden[b]^T + out_b
  gemm256<0, 1, 2><<<dim3(256), 512, 0, stream>>>(W2, hidden, d_out, out_b, SEQ,
                                                  (long)SEQ * DIM, (long)DIM * SEQ);
}